// Round 17
// baseline (6110.011 us; speedup 1.0000x reference)
//
#include <hip/hip_runtime.h>

// ---------------------------------------------------------------------------
// BiGRU encoder, MI355X. Round 17 = round 11 (proven, 5.53 ms) with the gh
// GEMM K-SPLIT ACROSS TWO WAVES (the 930cy serial-MFMA leg was the largest
// unattacked term; 8-wave split failed, this uses only r5-r16-proven 2-wave
// LDS ring machinery):
//   wave A: gh K[0,256)   24 MFMA + gates + pack + h store + drain + flags.
//   wave B: gh K[256,512) 24 MFMA -> pre-added partials -> LDS ring (2 slots,
//           guarded by ghdone released when A consumes).
//   wave C: gi full-K + residual -> fifo (r11 wave-B code verbatim).
// A polls flag replica (j&3); B polls ((j+2)&3).
//
// ws layout:
//   Xb   [T][B][F] bf16      33,554,432 B
//   Hf   [T][B][F] bf16      33,554,432 B
//   Hb   [T][B][F] bf16      33,554,432 B
//   Wb   [2][2][1536][512]    6,291,456 B   (dir, src{0=Whh,1=Wih})
//   flags 2 dirs x 4 replicas x 32 int
// ---------------------------------------------------------------------------

#define TT 2048
#define BB 16
#define FF 512
#define LL 10
#define RD 4
#define NTHR 192

typedef __attribute__((ext_vector_type(8))) short short8;
typedef __attribute__((ext_vector_type(4))) int   int4v;
typedef __attribute__((ext_vector_type(2))) int   int2v;
typedef __attribute__((ext_vector_type(4))) float f32x4;

// D = A*B + C with A (weights) pinned to AGPR, B (activations) in VGPR.
#define MFMA_WA(acc, wfa, afb) \
  asm("v_mfma_f32_16x16x32_bf16 %0, %1, %2, %0" : "+v"(acc) : "a"(wfa), "v"(afb))

__device__ __forceinline__ unsigned short f2bf(float f) {
  union { float f; unsigned int u; } v; v.f = f;
  unsigned int u = v.u;
  return (unsigned short)((u + 0x7fffu + ((u >> 16) & 1u)) >> 16);
}
__device__ __forceinline__ float bf2f(unsigned short h) {
  union { unsigned int u; float f; } v; v.u = ((unsigned int)h) << 16;
  return v.f;
}

__global__ void prep_x(const float* __restrict__ x, unsigned short* __restrict__ Xb) {
  int i = blockIdx.x * blockDim.x + threadIdx.x;
  int f = i & (FF - 1);
  int b = (i >> 9) & (BB - 1);
  int t = i >> 13;
  Xb[i] = f2bf(x[(size_t)b * (TT * 1025) + t * 1025 + f]);
}

__global__ void prep_w(const float* __restrict__ a, const float* __restrict__ b,
                       const float* __restrict__ c, const float* __restrict__ d,
                       unsigned short* __restrict__ Wb) {
  const int M = 1536 * 512;
  int i = blockIdx.x * blockDim.x + threadIdx.x;
  int m = i / M, r = i - m * M;
  const float* src = (m == 0) ? a : (m == 1) ? b : (m == 2) ? c : d;
  Wb[i] = f2bf(src[r]);
}

__global__ void prep_flags(int* __restrict__ flags) {
  int i = threadIdx.x;
  if (i < 256) flags[i] = 0;
}

// ---------------------------------------------------------------------------
__global__ void __launch_bounds__(NTHR, 1) bigru_rec(
    const unsigned short* __restrict__ Xb,
    unsigned short* __restrict__ Hf, unsigned short* __restrict__ Hb,
    const unsigned short* __restrict__ Wb,
    const float* __restrict__ bih_f, const float* __restrict__ bhh_f,
    const float* __restrict__ bih_b, const float* __restrict__ bhh_b,
    int* __restrict__ flags, float* __restrict__ out)
{
  const int bid  = blockIdx.x;
  const int d    = bid >> 5;           // direction
  const int j    = bid & 31;           // slice (16 hidden cols)
  const int tid  = threadIdx.x;
  const int w    = tid >> 6;           // 0=gh-lo+publish, 1=gh-hi, 2=gi
  const int lane = tid & 63;
  const int l15  = lane & 15;          // batch row (D col, operand-swapped)
  const int hi   = lane >> 4;          // quarter: 4 adjacent out-cols
  const int lk   = hi * 8;
  const int cb   = j * 16 + hi * 4;    // this lane's first out-col

  unsigned short* Hst = d ? Hb : Hf;
  int* flg = flags + d * 128;          // 4 replica lines of 32 ints
  const float* bih = d ? bih_b : bih_f;
  const float* bhh = d ? bhh_b : bhh_f;

  __shared__ float fifo[RD][64][17];   // C -> A : gi gates + residual x
  __shared__ float ghB[2][64][13];     // B -> A : gh K-hi partials (12 f32)
  __shared__ int wrote_s, consumed_s, ghBf_s, ghdone_s;
  if (tid == 0) { wrote_s = 0; consumed_s = 0; ghBf_s = 0; ghdone_s = 0; }
  __syncthreads();

  if (w == 0) {
    // ============ WAVE A: gh K[0,256) + gates + publish ====================
    int4v wf[3][8];
#pragma unroll
    for (int g = 0; g < 3; ++g) {
      const unsigned short* wrow =
          Wb + (size_t)((d * 2 + 0) * 1536 + g * 512 + j * 16 + l15) * 512 + lk;
#pragma unroll
      for (int kk = 0; kk < 8; ++kk)
        wf[g][kk] = *(const int4v*)(wrow + kk * 32);
    }
    __builtin_amdgcn_s_setprio(1);
    const f32x4 bh0 = *(const f32x4*)(bhh + cb);
    const f32x4 bh1 = *(const f32x4*)(bhh + 512 + cb);
    const f32x4 bh2 = *(const f32x4*)(bhh + 1024 + cb);
    float hc[4] = {0.f, 0.f, 0.f, 0.f};   // carry: batch l15, cols cb+jj
    int* myrep = flg + (j & 3) * 32;       // flag replica line for A

    for (int t = 0; t < TT; ++t) {
      f32x4 a0 = {0,0,0,0}, a1 = {0,0,0,0}, a2 = {0,0,0,0},
            a3 = {0,0,0,0}, a4 = {0,0,0,0}, a5 = {0,0,0,0};
      if (t > 0) {
        int vv = t;
        for (;;) {
          if (lane < 32)
            vv = __hip_atomic_load(myrep + lane, __ATOMIC_RELAXED,
                                   __HIP_MEMORY_SCOPE_AGENT);
          if (__all(lane < 32 ? (vv >= t) : 1)) break;
        }
        __builtin_amdgcn_sched_barrier(0);   // no load hoisting above the poll
        const unsigned short* Arow =
            Hst + (size_t)((t - 1) * BB + l15) * FF + lk;
        int4v af[8];
#pragma unroll
        for (int kk = 0; kk < 8; ++kk)
          af[kk] = *(const int4v*)(Arow + kk * 32);
#pragma unroll
        for (int kk = 0; kk < 8; kk += 2) {
          MFMA_WA(a0, wf[0][kk],     af[kk]);
          MFMA_WA(a2, wf[1][kk],     af[kk]);
          MFMA_WA(a4, wf[2][kk],     af[kk]);
          MFMA_WA(a1, wf[0][kk + 1], af[kk + 1]);
          MFMA_WA(a3, wf[1][kk + 1], af[kk + 1]);
          MFMA_WA(a5, wf[2][kk + 1], af[kk + 1]);
        }
        asm volatile("s_nop 7\n\ts_nop 7");  // MFMA D -> VALU hazard guard
      }
      // wait for B's K-hi partials (slot t&1)
      while (__hip_atomic_load(&ghBf_s, __ATOMIC_ACQUIRE,
                               __HIP_MEMORY_SCOPE_WORKGROUP) < t + 1) {}
      float gB[12];
#pragma unroll
      for (int q = 0; q < 12; ++q) gB[q] = ghB[t & 1][lane][q];
      __hip_atomic_store(&ghdone_s, t + 1, __ATOMIC_RELEASE,
                         __HIP_MEMORY_SCOPE_WORKGROUP);
      // gi + residual from wave C
      const int slot = t & (RD - 1);
      while (__hip_atomic_load(&wrote_s, __ATOMIC_ACQUIRE,
                               __HIP_MEMORY_SCOPE_WORKGROUP) < t + 1) {}
      float fr[4], fz[4], fn[4], fx[4];
#pragma unroll
      for (int jj = 0; jj < 4; ++jj) {
        fr[jj] = fifo[slot][lane][jj];
        fz[jj] = fifo[slot][lane][4 + jj];
        fn[jj] = fifo[slot][lane][8 + jj];
        fx[jj] = fifo[slot][lane][12 + jj];
      }
      __hip_atomic_store(&consumed_s, t + 1, __ATOMIC_RELEASE,
                         __HIP_MEMORY_SCOPE_WORKGROUP);

      unsigned short us[4]; f32x4 h2v;
#pragma unroll
      for (int jj = 0; jj < 4; ++jj) {
        const float ghr = a0[jj] + a1[jj] + gB[jj]     + bh0[jj];
        const float ghz = a2[jj] + a3[jj] + gB[4 + jj] + bh1[jj];
        const float ghn = a4[jj] + a5[jj] + gB[8 + jj] + bh2[jj];
        const float rr = 1.f / (1.f + __expf(-(fr[jj] + ghr)));
        const float zz = 1.f / (1.f + __expf(-(fz[jj] + ghz)));
        const float ee = __expf(2.f * (fn[jj] + rr * ghn));
        const float nn = 1.f - 2.f / (ee + 1.f);        // tanh, inf-safe
        const float h2 = (1.f - zz) * nn + zz * hc[jj] + fx[jj];
        hc[jj] = h2; h2v[jj] = h2; us[jj] = f2bf(h2);
      }
      // pack 4 adjacent cols + partner 8B -> one 16B write-through store
      const unsigned int dw0 = (unsigned int)us[0] | ((unsigned int)us[1] << 16);
      const unsigned int dw1 = (unsigned int)us[2] | ((unsigned int)us[3] << 16);
      const unsigned int p0 = (unsigned int)__shfl_xor((int)dw0, 16);
      const unsigned int p1 = (unsigned int)__shfl_xor((int)dw1, 16);
      if (!(hi & 1)) {
        int4v pk; pk[0] = (int)dw0; pk[1] = (int)dw1;
        pk[2] = (int)p0; pk[3] = (int)p1;
        unsigned short* wp =
            Hst + (size_t)(t * BB + l15) * FF + j * 16 + (hi >> 1) * 8;
        asm volatile("global_store_dwordx4 %0, %1, off sc0 sc1"
                     :: "v"(wp), "v"(pk) : "memory");
      }
      asm volatile("s_waitcnt vmcnt(0)" ::: "memory");   // h at coherence point
      if (lane == 0) {                 // publish to all 4 replica lines
#pragma unroll
        for (int r = 0; r < 4; ++r)
          __hip_atomic_store(flg + r * 32 + j, t + 1, __ATOMIC_RELAXED,
                             __HIP_MEMORY_SCOPE_AGENT);
      }
      // out store (off critical path, after flag): one dwordx4 per lane
      if (t >= LL && t < TT - LL) {
        float* op = out + ((size_t)l15 * (TT - 2 * LL) + (t - LL)) * 1024
                  + d * 512 + cb;
        *(f32x4*)op = h2v;
      }
    }
  } else if (w == 1) {
    // ============ WAVE B: gh K[256,512) -> LDS ring ========================
    int4v wf[3][8];
#pragma unroll
    for (int g = 0; g < 3; ++g) {
      const unsigned short* wrow =
          Wb + (size_t)((d * 2 + 0) * 1536 + g * 512 + j * 16 + l15) * 512
             + 256 + lk;
#pragma unroll
      for (int kk = 0; kk < 8; ++kk)
        wf[g][kk] = *(const int4v*)(wrow + kk * 32);
    }
    __builtin_amdgcn_s_setprio(1);
    int* myrep = flg + ((j + 2) & 3) * 32;   // different replica line than A

    for (int t = 0; t < TT; ++t) {
      f32x4 a0 = {0,0,0,0}, a1 = {0,0,0,0}, a2 = {0,0,0,0},
            a3 = {0,0,0,0}, a4 = {0,0,0,0}, a5 = {0,0,0,0};
      if (t > 0) {
        int vv = t;
        for (;;) {
          if (lane < 32)
            vv = __hip_atomic_load(myrep + lane, __ATOMIC_RELAXED,
                                   __HIP_MEMORY_SCOPE_AGENT);
          if (__all(lane < 32 ? (vv >= t) : 1)) break;
        }
        __builtin_amdgcn_sched_barrier(0);
        const unsigned short* Arow =
            Hst + (size_t)((t - 1) * BB + l15) * FF + 256 + lk;
        int4v af[8];
#pragma unroll
        for (int kk = 0; kk < 8; ++kk)
          af[kk] = *(const int4v*)(Arow + kk * 32);
#pragma unroll
        for (int kk = 0; kk < 8; kk += 2) {
          MFMA_WA(a0, wf[0][kk],     af[kk]);
          MFMA_WA(a2, wf[1][kk],     af[kk]);
          MFMA_WA(a4, wf[2][kk],     af[kk]);
          MFMA_WA(a1, wf[0][kk + 1], af[kk + 1]);
          MFMA_WA(a3, wf[1][kk + 1], af[kk + 1]);
          MFMA_WA(a5, wf[2][kk + 1], af[kk + 1]);
        }
        asm volatile("s_nop 7\n\ts_nop 7");  // MFMA D -> VALU hazard guard
      }
      // slot t&1 last read by A at step t-2 -> need ghdone >= t-1
      while (__hip_atomic_load(&ghdone_s, __ATOMIC_ACQUIRE,
                               __HIP_MEMORY_SCOPE_WORKGROUP) < t - 1) {}
#pragma unroll
      for (int jj = 0; jj < 4; ++jj) {
        ghB[t & 1][lane][jj]     = a0[jj] + a1[jj];
        ghB[t & 1][lane][4 + jj] = a2[jj] + a3[jj];
        ghB[t & 1][lane][8 + jj] = a4[jj] + a5[jj];
      }
      __hip_atomic_store(&ghBf_s, t + 1, __ATOMIC_RELEASE,
                         __HIP_MEMORY_SCOPE_WORKGROUP);
    }
  } else {
    // ============ WAVE C: gi full-K + residual -> fifo (r11 verbatim) ======
    int4v wf[3][16];
#pragma unroll
    for (int g = 0; g < 3; ++g) {
      const unsigned short* wrow =
          Wb + (size_t)((d * 2 + 1) * 1536 + g * 512 + j * 16 + l15) * 512 + lk;
#pragma unroll
      for (int kk = 0; kk < 16; ++kk)
        wf[g][kk] = *(const int4v*)(wrow + kk * 32);
    }
    const f32x4 bi0 = *(const f32x4*)(bih + cb);
    const f32x4 bi1 = *(const f32x4*)(bih + 512 + cb);
    const f32x4 bi2 = *(const f32x4*)(bih + 1024 + cb);
    for (int t = 0; t < TT; ++t) {
      const int slot = t & (RD - 1);
      while (t - __hip_atomic_load(&consumed_s, __ATOMIC_ACQUIRE,
                                   __HIP_MEMORY_SCOPE_WORKGROUP) >= RD) {}
      const int tx = d ? (TT - 1 - t) : t;
      const unsigned short* Arow = Xb + (size_t)(tx * BB + l15) * FF + lk;
      int4v af[16];
#pragma unroll
      for (int kk = 0; kk < 16; ++kk)
        af[kk] = *(const int4v*)(Arow + kk * 32);
      f32x4 a0 = {0,0,0,0}, a1 = {0,0,0,0}, a2 = {0,0,0,0},
            a3 = {0,0,0,0}, a4 = {0,0,0,0}, a5 = {0,0,0,0};
#pragma unroll
      for (int kk = 0; kk < 16; kk += 2) {
        MFMA_WA(a0, wf[0][kk],     af[kk]);
        MFMA_WA(a2, wf[1][kk],     af[kk]);
        MFMA_WA(a4, wf[2][kk],     af[kk]);
        MFMA_WA(a1, wf[0][kk + 1], af[kk + 1]);
        MFMA_WA(a3, wf[1][kk + 1], af[kk + 1]);
        MFMA_WA(a5, wf[2][kk + 1], af[kk + 1]);
      }
      asm volatile("s_nop 7\n\ts_nop 7");
      // residual x: 4 adjacent bf16 = one 8B load
      const int2v xw = *(const int2v*)(Xb + (size_t)(tx * BB + l15) * FF + cb);
      float xv[4];
      xv[0] = bf2f((unsigned short)(xw[0] & 0xffff));
      xv[1] = bf2f((unsigned short)((unsigned int)xw[0] >> 16));
      xv[2] = bf2f((unsigned short)(xw[1] & 0xffff));
      xv[3] = bf2f((unsigned short)((unsigned int)xw[1] >> 16));
#pragma unroll
      for (int jj = 0; jj < 4; ++jj) {
        fifo[slot][lane][jj]      = a0[jj] + a1[jj] + bi0[jj];
        fifo[slot][lane][4 + jj]  = a2[jj] + a3[jj] + bi1[jj];
        fifo[slot][lane][8 + jj]  = a4[jj] + a5[jj] + bi2[jj];
        fifo[slot][lane][12 + jj] = xv[jj];
      }
      __hip_atomic_store(&wrote_s, t + 1, __ATOMIC_RELEASE,
                         __HIP_MEMORY_SCOPE_WORKGROUP);
    }
  }
}

// ---------------------------------------------------------------------------
extern "C" void kernel_launch(void* const* d_in, const int* in_sizes, int n_in,
                              void* d_out, int out_size, void* d_ws, size_t ws_size,
                              hipStream_t stream) {
  const float* x     = (const float*)d_in[0];
  const float* Wih_f = (const float*)d_in[1];
  const float* Whh_f = (const float*)d_in[2];
  const float* bih_f = (const float*)d_in[3];
  const float* bhh_f = (const float*)d_in[4];
  const float* Wih_b = (const float*)d_in[5];
  const float* Whh_b = (const float*)d_in[6];
  const float* bih_b = (const float*)d_in[7];
  const float* bhh_b = (const float*)d_in[8];
  float* out = (float*)d_out;

  char* ws = (char*)d_ws;
  unsigned short* Xb = (unsigned short*)ws;
  unsigned short* Hf = (unsigned short*)(ws + (size_t)33554432);
  unsigned short* Hb = (unsigned short*)(ws + (size_t)2 * 33554432);
  unsigned short* Wb = (unsigned short*)(ws + (size_t)3 * 33554432);
  int* flags         = (int*)(ws + (size_t)3 * 33554432 + 6291456);

  prep_x<<<65536, 256, 0, stream>>>(x, Xb);
  prep_w<<<12288, 256, 0, stream>>>(Whh_f, Wih_f, Whh_b, Wih_b, Wb);
  prep_flags<<<1, 256, 0, stream>>>(flags);
  bigru_rec<<<64, NTHR, 0, stream>>>(Xb, Hf, Hb, Wb, bih_f, bhh_f, bih_b, bhh_b,
                                     flags, out);
}

// Round 18
// 5511.832 us; speedup vs baseline: 1.1085x; 1.1085x over previous
//
#include <hip/hip_runtime.h>

// ---------------------------------------------------------------------------
// BiGRU encoder, MI355X. FINAL = round 11 restored (best measured: 5.53 ms).
// Persistent 64-block recurrence, swapped-operand MFMA (weights in AGPR as
// A-operand -> lane holds 4 ADJACENT out-cols), write-through h publish +
// replica flags + relaxed agent polls. Latency-bound at ~6500 cy/step
// (3-4 loaded L3 RTTs + compute); six protocol/structure variants (r12-r17)
// all neutral or worse — this is the practical floor of the family.
//
// 64 blocks, 128 threads (2 waves), 1 block/CU.
//   wave A: gh = Whh(A,AGPR) x h(B) + gates + h publish + flags + out[].
//   wave B: gi = Wih x x + residual -> LDS FIFO (runs ahead, RD=4).
//
// ws layout:
//   Xb   [T][B][F] bf16      33,554,432 B
//   Hf   [T][B][F] bf16      33,554,432 B
//   Hb   [T][B][F] bf16      33,554,432 B
//   Wb   [2][2][1536][512]    6,291,456 B   (dir, src{0=Whh,1=Wih})
//   flags 2 dirs x 4 replicas x 32 int
// ---------------------------------------------------------------------------

#define TT 2048
#define BB 16
#define FF 512
#define LL 10
#define RD 4
#define NTHR 128

typedef __attribute__((ext_vector_type(8))) short short8;
typedef __attribute__((ext_vector_type(4))) int   int4v;
typedef __attribute__((ext_vector_type(2))) int   int2v;
typedef __attribute__((ext_vector_type(4))) float f32x4;

// D = A*B + C with A (weights) pinned to AGPR, B (activations) in VGPR.
#define MFMA_WA(acc, wfa, afb) \
  asm("v_mfma_f32_16x16x32_bf16 %0, %1, %2, %0" : "+v"(acc) : "a"(wfa), "v"(afb))

__device__ __forceinline__ unsigned short f2bf(float f) {
  union { float f; unsigned int u; } v; v.f = f;
  unsigned int u = v.u;
  return (unsigned short)((u + 0x7fffu + ((u >> 16) & 1u)) >> 16);
}
__device__ __forceinline__ float bf2f(unsigned short h) {
  union { unsigned int u; float f; } v; v.u = ((unsigned int)h) << 16;
  return v.f;
}

__global__ void prep_x(const float* __restrict__ x, unsigned short* __restrict__ Xb) {
  int i = blockIdx.x * blockDim.x + threadIdx.x;
  int f = i & (FF - 1);
  int b = (i >> 9) & (BB - 1);
  int t = i >> 13;
  Xb[i] = f2bf(x[(size_t)b * (TT * 1025) + t * 1025 + f]);
}

__global__ void prep_w(const float* __restrict__ a, const float* __restrict__ b,
                       const float* __restrict__ c, const float* __restrict__ d,
                       unsigned short* __restrict__ Wb) {
  const int M = 1536 * 512;
  int i = blockIdx.x * blockDim.x + threadIdx.x;
  int m = i / M, r = i - m * M;
  const float* src = (m == 0) ? a : (m == 1) ? b : (m == 2) ? c : d;
  Wb[i] = f2bf(src[r]);
}

__global__ void prep_flags(int* __restrict__ flags) {
  int i = threadIdx.x;
  if (i < 256) flags[i] = 0;
}

// ---------------------------------------------------------------------------
__global__ void __launch_bounds__(NTHR, 1) bigru_rec(
    const unsigned short* __restrict__ Xb,
    unsigned short* __restrict__ Hf, unsigned short* __restrict__ Hb,
    const unsigned short* __restrict__ Wb,
    const float* __restrict__ bih_f, const float* __restrict__ bhh_f,
    const float* __restrict__ bih_b, const float* __restrict__ bhh_b,
    int* __restrict__ flags, float* __restrict__ out)
{
  const int bid  = blockIdx.x;
  const int d    = bid >> 5;           // direction
  const int j    = bid & 31;           // slice (16 hidden cols)
  const int tid  = threadIdx.x;
  const int w    = tid >> 6;           // 0 = gh wave, 1 = gi wave
  const int lane = tid & 63;
  const int l15  = lane & 15;          // batch row (D col after operand swap)
  const int hi   = lane >> 4;          // quarter: D rows hi*4+jj
  const int lk   = hi * 8;
  const int cb   = j * 16 + hi * 4;    // this lane's first out-col

  unsigned short* Hst = d ? Hb : Hf;
  int* flg = flags + d * 128;          // 4 replica lines of 32 ints
  const float* bih = d ? bih_b : bih_f;
  const float* bhh = d ? bhh_b : bhh_f;

  __shared__ float fifo[RD][64][17];   // B -> A : gi gates + residual x
  __shared__ int wrote_s, consumed_s;
  if (tid == 0) { wrote_s = 0; consumed_s = 0; }
  __syncthreads();

  // Weights: plain loads; used only via "a" MFMA constraint -> homed in AGPRs.
  // A-operand layout: lane&15 = A row = out-col (W row), K = (lane>>4)*8.
  const int src = w;                   // 0=Whh, 1=Wih
  int4v wf[3][16];
#pragma unroll
  for (int g = 0; g < 3; ++g) {
    const unsigned short* wrow =
        Wb + (size_t)((d * 2 + src) * 1536 + g * 512 + j * 16 + l15) * 512 + lk;
#pragma unroll
    for (int kk = 0; kk < 16; ++kk)
      wf[g][kk] = *(const int4v*)(wrow + kk * 32);
  }

  if (w == 0) {
    // ====================== WAVE A: gh + gates + publish ===================
    __builtin_amdgcn_s_setprio(1);
    // 4 adjacent-col biases per lane
    const f32x4 bh0 = *(const f32x4*)(bhh + cb);
    const f32x4 bh1 = *(const f32x4*)(bhh + 512 + cb);
    const f32x4 bh2 = *(const f32x4*)(bhh + 1024 + cb);
    float hc[4] = {0.f, 0.f, 0.f, 0.f};   // carry: batch l15, cols cb+jj
    int* myrep = flg + (j & 3) * 32;   // this consumer's flag replica line

    for (int t = 0; t < TT; ++t) {
      f32x4 a0 = {0,0,0,0}, a1 = {0,0,0,0}, a2 = {0,0,0,0},
            a3 = {0,0,0,0}, a4 = {0,0,0,0}, a5 = {0,0,0,0};
      if (t > 0) {
        int vv = t;
        for (;;) {
          if (lane < 32)
            vv = __hip_atomic_load(myrep + lane, __ATOMIC_RELAXED,
                                   __HIP_MEMORY_SCOPE_AGENT);
          if (__all(lane < 32 ? (vv >= t) : 1)) break;
        }
        __builtin_amdgcn_sched_barrier(0);   // no load hoisting above the poll
        // B-operand (h rows): lane&15 = batch row, K = (lane>>4)*8
        const unsigned short* Arow =
            Hst + (size_t)((t - 1) * BB + l15) * FF + lk;
        int4v af[16];
#pragma unroll
        for (int kk = 0; kk < 16; ++kk)
          af[kk] = *(const int4v*)(Arow + kk * 32);
#pragma unroll
        for (int kk = 0; kk < 16; kk += 2) {
          MFMA_WA(a0, wf[0][kk],     af[kk]);
          MFMA_WA(a2, wf[1][kk],     af[kk]);
          MFMA_WA(a4, wf[2][kk],     af[kk]);
          MFMA_WA(a1, wf[0][kk + 1], af[kk + 1]);
          MFMA_WA(a3, wf[1][kk + 1], af[kk + 1]);
          MFMA_WA(a5, wf[2][kk + 1], af[kk + 1]);
        }
        asm volatile("s_nop 7\n\ts_nop 7");  // MFMA D -> VALU hazard guard
      }
      const int slot = t & (RD - 1);
      while (__hip_atomic_load(&wrote_s, __ATOMIC_ACQUIRE,
                               __HIP_MEMORY_SCOPE_WORKGROUP) < t + 1) {}
      float fr[4], fz[4], fn[4], fx[4];
#pragma unroll
      for (int jj = 0; jj < 4; ++jj) {
        fr[jj] = fifo[slot][lane][jj];
        fz[jj] = fifo[slot][lane][4 + jj];
        fn[jj] = fifo[slot][lane][8 + jj];
        fx[jj] = fifo[slot][lane][12 + jj];
      }
      __hip_atomic_store(&consumed_s, t + 1, __ATOMIC_RELEASE,
                         __HIP_MEMORY_SCOPE_WORKGROUP);

      unsigned short us[4]; f32x4 h2v;
#pragma unroll
      for (int jj = 0; jj < 4; ++jj) {
        const float ghr = a0[jj] + a1[jj] + bh0[jj];
        const float ghz = a2[jj] + a3[jj] + bh1[jj];
        const float ghn = a4[jj] + a5[jj] + bh2[jj];
        const float rr = 1.f / (1.f + __expf(-(fr[jj] + ghr)));
        const float zz = 1.f / (1.f + __expf(-(fz[jj] + ghz)));
        const float ee = __expf(2.f * (fn[jj] + rr * ghn));
        const float nn = 1.f - 2.f / (ee + 1.f);        // tanh, inf-safe
        const float h2 = (1.f - zz) * nn + zz * hc[jj] + fx[jj];
        hc[jj] = h2; h2v[jj] = h2; us[jj] = f2bf(h2);
      }
      // --- h publish: lane holds 4 ADJACENT cols -> 2 dwords in-lane,
      //     one shfl_xor(16) merges partner's 8B -> 16B store per even-hi lane.
      const unsigned int dw0 = (unsigned int)us[0] | ((unsigned int)us[1] << 16);
      const unsigned int dw1 = (unsigned int)us[2] | ((unsigned int)us[3] << 16);
      const unsigned int p0 = (unsigned int)__shfl_xor((int)dw0, 16);
      const unsigned int p1 = (unsigned int)__shfl_xor((int)dw1, 16);
      if (!(hi & 1)) {
        int4v pk; pk[0] = (int)dw0; pk[1] = (int)dw1;
        pk[2] = (int)p0; pk[3] = (int)p1;
        unsigned short* wp =
            Hst + (size_t)(t * BB + l15) * FF + j * 16 + (hi >> 1) * 8;
        asm volatile("global_store_dwordx4 %0, %1, off sc0 sc1"
                     :: "v"(wp), "v"(pk) : "memory");
      }
      asm volatile("s_waitcnt vmcnt(0)" ::: "memory");   // h at coherence point
      if (lane == 0) {                 // publish to all 4 replica lines
#pragma unroll
        for (int r = 0; r < 4; ++r)
          __hip_atomic_store(flg + r * 32 + j, t + 1, __ATOMIC_RELAXED,
                             __HIP_MEMORY_SCOPE_AGENT);
      }
      // out store (off critical path, after flag): one dwordx4 per lane
      if (t >= LL && t < TT - LL) {
        float* op = out + ((size_t)l15 * (TT - 2 * LL) + (t - LL)) * 1024
                  + d * 512 + cb;
        *(f32x4*)op = h2v;
      }
    }
  } else {
    // ====================== WAVE B: gi + residual -> FIFO ==================
    const f32x4 bi0 = *(const f32x4*)(bih + cb);
    const f32x4 bi1 = *(const f32x4*)(bih + 512 + cb);
    const f32x4 bi2 = *(const f32x4*)(bih + 1024 + cb);
    for (int t = 0; t < TT; ++t) {
      const int slot = t & (RD - 1);
      while (t - __hip_atomic_load(&consumed_s, __ATOMIC_ACQUIRE,
                                   __HIP_MEMORY_SCOPE_WORKGROUP) >= RD) {}
      const int tx = d ? (TT - 1 - t) : t;
      const unsigned short* Arow = Xb + (size_t)(tx * BB + l15) * FF + lk;
      int4v af[16];
#pragma unroll
      for (int kk = 0; kk < 16; ++kk)
        af[kk] = *(const int4v*)(Arow + kk * 32);
      f32x4 a0 = {0,0,0,0}, a1 = {0,0,0,0}, a2 = {0,0,0,0},
            a3 = {0,0,0,0}, a4 = {0,0,0,0}, a5 = {0,0,0,0};
#pragma unroll
      for (int kk = 0; kk < 16; kk += 2) {
        MFMA_WA(a0, wf[0][kk],     af[kk]);
        MFMA_WA(a2, wf[1][kk],     af[kk]);
        MFMA_WA(a4, wf[2][kk],     af[kk]);
        MFMA_WA(a1, wf[0][kk + 1], af[kk + 1]);
        MFMA_WA(a3, wf[1][kk + 1], af[kk + 1]);
        MFMA_WA(a5, wf[2][kk + 1], af[kk + 1]);
      }
      asm volatile("s_nop 7\n\ts_nop 7");
      // residual x: 4 adjacent bf16 = one 8B load
      const int2v xw = *(const int2v*)(Xb + (size_t)(tx * BB + l15) * FF + cb);
      float xv[4];
      xv[0] = bf2f((unsigned short)(xw[0] & 0xffff));
      xv[1] = bf2f((unsigned short)((unsigned int)xw[0] >> 16));
      xv[2] = bf2f((unsigned short)(xw[1] & 0xffff));
      xv[3] = bf2f((unsigned short)((unsigned int)xw[1] >> 16));
#pragma unroll
      for (int jj = 0; jj < 4; ++jj) {
        fifo[slot][lane][jj]      = a0[jj] + a1[jj] + bi0[jj];
        fifo[slot][lane][4 + jj]  = a2[jj] + a3[jj] + bi1[jj];
        fifo[slot][lane][8 + jj]  = a4[jj] + a5[jj] + bi2[jj];
        fifo[slot][lane][12 + jj] = xv[jj];
      }
      __hip_atomic_store(&wrote_s, t + 1, __ATOMIC_RELEASE,
                         __HIP_MEMORY_SCOPE_WORKGROUP);
    }
  }
}

// ---------------------------------------------------------------------------
extern "C" void kernel_launch(void* const* d_in, const int* in_sizes, int n_in,
                              void* d_out, int out_size, void* d_ws, size_t ws_size,
                              hipStream_t stream) {
  const float* x     = (const float*)d_in[0];
  const float* Wih_f = (const float*)d_in[1];
  const float* Whh_f = (const float*)d_in[2];
  const float* bih_f = (const float*)d_in[3];
  const float* bhh_f = (const float*)d_in[4];
  const float* Wih_b = (const float*)d_in[5];
  const float* Whh_b = (const float*)d_in[6];
  const float* bih_b = (const float*)d_in[7];
  const float* bhh_b = (const float*)d_in[8];
  float* out = (float*)d_out;

  char* ws = (char*)d_ws;
  unsigned short* Xb = (unsigned short*)ws;
  unsigned short* Hf = (unsigned short*)(ws + (size_t)33554432);
  unsigned short* Hb = (unsigned short*)(ws + (size_t)2 * 33554432);
  unsigned short* Wb = (unsigned short*)(ws + (size_t)3 * 33554432);
  int* flags         = (int*)(ws + (size_t)3 * 33554432 + 6291456);

  prep_x<<<65536, 256, 0, stream>>>(x, Xb);
  prep_w<<<12288, 256, 0, stream>>>(Whh_f, Wih_f, Whh_b, Wih_b, Wb);
  prep_flags<<<1, 256, 0, stream>>>(flags);
  bigru_rec<<<64, NTHR, 0, stream>>>(Xb, Hf, Hb, Wb, bih_f, bhh_f, bih_b, bhh_b,
                                     flags, out);
}